// Round 9
// baseline (221.461 us; speedup 1.0000x reference)
//
#include <hip/hip_runtime.h>
#include <cstdint>
#include <cstddef>

typedef _Float16 half4v __attribute__((ext_vector_type(4)));
typedef _Float16 half8v __attribute__((ext_vector_type(8)));
typedef float    f32x4  __attribute__((ext_vector_type(4)));

#define N_PTS   262144
#define CDIM    64
#define KCODES  512
#define TAUA    5e-3f          // acc-units; true-dist gap = 2*acc gap -> 1e-2
#define FLAG_CAP 65536u

// output offsets (floats): out, diff, embedding_ind, new_embedding, new_cluster_size, new_embedding_avg
#define OFF_DIFF 16777216u
#define OFF_IND  16777217u
#define OFF_EMB  17039361u
#define OFF_CSZ  17072129u
#define OFF_AVG  17072641u

// ---------------------------------------------------------------- main: MFMA f16x2-split distances + argmin
// acc = ee/2 + (-x)*e  ->  dist = 2*acc + xx  (argmin equivalent in acc units)
// r8-proven hot loop; NEW: fused quantize-output write phase (k_quant folded in; 64MB write rides free at 5% BW).
__global__ __launch_bounds__(512) void k_main(
    const float* __restrict__ in, const float* __restrict__ emb,
    float* __restrict__ out,
    int* __restrict__ ind_buf, float* __restrict__ diff_acc,
    unsigned* __restrict__ nflag, int* __restrict__ flaglist)
{
    // LDS: B_hi [64KiB] | B_lo [64KiB] | ee2 [2KiB]   (swizzled: byte ^= (col&7)<<4)
    __shared__ __align__(16) char bsm[133120];
    __shared__ __align__(16) int ind_sh[1024];          // per-WG indices for fused quantize write
    float* ee2_lds = (float*)(bsm + 131072);
    const int tid = threadIdx.x;

    // ---- stage codebook: fp32 -> f16 hi/lo, swizzled; ee2 computed inline ----
    {
        const int col = tid;                 // 512 threads = 512 cols
        const int xr  = (col & 7) << 4;
        float s = 0.f;
        #pragma unroll
        for (int c0 = 0; c0 < CDIM; c0 += 4) {
            float v[4];
            #pragma unroll
            for (int i = 0; i < 4; ++i) v[i] = emb[(c0 + i)*KCODES + col];
            half4v h, lo;
            #pragma unroll
            for (int i = 0; i < 4; ++i) {
                s = fmaf(v[i], v[i], s);
                _Float16 hh = (_Float16)v[i];
                h[i]  = hh;
                lo[i] = (_Float16)(v[i] - (float)hh);
            }
            const int wb = col*128 + ((c0*2) ^ xr);
            *(half4v*)(bsm + wb)         = h;
            *(half4v*)(bsm + 65536 + wb) = lo;
        }
        ee2_lds[col] = 0.5f * s;
    }
    __syncthreads();

    const int w  = tid >> 6, l = tid & 63;
    const int g  = l >> 4,  lc = l & 15;

    for (int r = 0; r < 2; ++r) {
        const int pbase = (blockIdx.x << 10) + (r << 9) + (w << 6);  // 64 points/wave
        const int b     = pbase >> 12;
        const float* inb = in + ((size_t)b << 18) + ((pbase & 4095) + lc);

        // ---- A fragments: negated x, exact f16 split; xx accumulated on the fly ----
        half8v ah[4][2], al[4][2];
        float xs = 0.f;
        #pragma unroll
        for (int t = 0; t < 4; ++t)
            #pragma unroll
            for (int s = 0; s < 2; ++s)
                #pragma unroll
                for (int j = 0; j < 8; ++j) {
                    const int c = s*32 + g*8 + j;
                    const float x = inb[(size_t)c*4096 + t*16];
                    xs = fmaf(x, x, xs);
                    const float xf = -x;
                    const _Float16 hh = (_Float16)xf;
                    ah[t][s][j] = hh;
                    al[t][s][j] = (_Float16)(xf - (float)hh);
                }

        float d1[4][4], d2[4][4]; int k1[4][4];
        #pragma unroll
        for (int t = 0; t < 4; ++t)
            #pragma unroll
            for (int rr = 0; rr < 4; ++rr) { d1[t][rr] = 3.4e38f; d2[t][rr] = 3.4e38f; k1[t][rr] = 0; }

        for (int ct = 0; ct < 32; ++ct) {
            const int col  = (ct << 4) + lc;
            const float sd = ee2_lds[col];
            const int rb   = col*128 + ((g*16) ^ ((col & 7) << 4));
            half8v bh0 = *(const half8v*)(bsm + rb);
            half8v bh1 = *(const half8v*)(bsm + (rb ^ 64));
            half8v bl0 = *(const half8v*)(bsm + 65536 + rb);
            half8v bl1 = *(const half8v*)(bsm + 65536 + (rb ^ 64));

            #pragma unroll
            for (int t = 0; t < 4; ++t) {
                // two independent 3-deep chains (K-halves s=0 / s=1)
                f32x4 acc0 = {sd, sd, sd, sd};
                f32x4 acc1 = {0.f, 0.f, 0.f, 0.f};
                acc0 = __builtin_amdgcn_mfma_f32_16x16x32_f16(al[t][0], bh0, acc0, 0, 0, 0);
                acc1 = __builtin_amdgcn_mfma_f32_16x16x32_f16(al[t][1], bh1, acc1, 0, 0, 0);
                acc0 = __builtin_amdgcn_mfma_f32_16x16x32_f16(ah[t][0], bl0, acc0, 0, 0, 0);
                acc1 = __builtin_amdgcn_mfma_f32_16x16x32_f16(ah[t][1], bl1, acc1, 0, 0, 0);
                acc0 = __builtin_amdgcn_mfma_f32_16x16x32_f16(ah[t][0], bh0, acc0, 0, 0, 0);
                acc1 = __builtin_amdgcn_mfma_f32_16x16x32_f16(ah[t][1], bh1, acc1, 0, 0, 0);
                #pragma unroll
                for (int rr = 0; rr < 4; ++rr) {
                    const float d = acc0[rr] + acc1[rr];
                    const bool cc = d < d1[t][rr];
                    d2[t][rr] = fminf(d2[t][rr], fmaxf(d, d1[t][rr]));
                    d1[t][rr] = fminf(d1[t][rr], d);
                    k1[t][rr] = cc ? col : k1[t][rr];
                }
            }
        }

        // ---- cross-lane best-2 merge over the 16 col-lanes ----
        #pragma unroll
        for (int m = 1; m <= 8; m <<= 1) {
            #pragma unroll
            for (int t = 0; t < 4; ++t)
                #pragma unroll
                for (int rr = 0; rr < 4; ++rr) {
                    const float od1 = __shfl_xor(d1[t][rr], m);
                    const int   ok1 = __shfl_xor(k1[t][rr], m);
                    const float od2 = __shfl_xor(d2[t][rr], m);
                    const float nd2 = fminf(fmaxf(d1[t][rr], od1), fminf(d2[t][rr], od2));
                    const bool take = (od1 < d1[t][rr]) || (od1 == d1[t][rr] && ok1 < k1[t][rr]);
                    d1[t][rr] = take ? od1 : d1[t][rr];
                    k1[t][rr] = take ? ok1 : k1[t][rr];
                    d2[t][rr] = nd2;
                }
        }

        // ---- outputs: indices (global + LDS), near-tie flags, diff partial ----
        float ds = 0.f;
        if (lc == 0) {
            #pragma unroll
            for (int t = 0; t < 4; ++t) {
                const int nb = pbase + t*16 + (g << 2);
                int4 iv = make_int4(k1[t][0], k1[t][1], k1[t][2], k1[t][3]);
                *(int4*)(ind_buf + nb) = iv;
                *(int4*)&ind_sh[(r << 9) + (w << 6) + t*16 + (g << 2)] = iv;
                #pragma unroll
                for (int rr = 0; rr < 4; ++rr) {
                    out[OFF_IND + nb + rr] = (float)k1[t][rr];
                    ds += d1[t][rr];
                    if (d2[t][rr] - d1[t][rr] < TAUA) {
                        unsigned ix = atomicAdd(nflag, 1u);
                        if (ix < FLAG_CAP) flaglist[ix] = nb + rr;
                    }
                }
            }
        }
        #pragma unroll
        for (int m = 1; m < 64; m <<= 1) {
            ds += __shfl_xor(ds, m);
            xs += __shfl_xor(xs, m);
        }
        if (l == 0) atomicAdd(diff_acc, 2.f*ds + xs);
    }

    // ---- fused quantize write: out[b][c][hw] = emb[c][ind] (coalesced per channel) ----
    __syncthreads();
    {
        const int n0  = blockIdx.x << 10;
        const int bq  = n0 >> 12;
        const int hw0 = n0 & 4095;
        float* outb = out + ((size_t)bq << 18) + hw0;
        #pragma unroll 4
        for (int it = 0; it < 32; ++it) {
            const int idx = it*512 + tid;        // 16384 float4 slots: 64 ch x 256
            const int c   = idx >> 8;
            const int p4  = (idx & 255) << 2;
            const int4 iv = *(const int4*)&ind_sh[p4];
            const float* er = emb + (c << 9);
            float4 o = make_float4(er[iv.x], er[iv.y], er[iv.z], er[iv.w]);
            *(float4*)(outb + ((size_t)c << 12) + p4) = o;
        }
    }
}

// ---------------------------------------------------------------- f64 exact re-scan for near-ties
// NEW: also patches the fused quantize output for corrected points (one channel per lane).
__global__ void k_refine(const float* __restrict__ in, const float* __restrict__ emb,
                         const unsigned* __restrict__ nflag, const int* __restrict__ flaglist,
                         int* __restrict__ ind_buf, float* __restrict__ out)
{
    const int gtid = blockIdx.x*blockDim.x + threadIdx.x;
    const int wid  = gtid >> 6;
    const int lane = threadIdx.x & 63;
    const int nw   = (gridDim.x * blockDim.x) >> 6;
    unsigned nf = *nflag; if (nf > FLAG_CAP) nf = FLAG_CAP;
    for (unsigned f = wid; f < nf; f += nw) {
        const int n = flaglist[f];
        const int b = n >> 12, hw = n & 4095;
        const float* xb = in + ((size_t)b << 18) + hw;
        const float* er = emb + lane*8;
        double dd[8] = {0,0,0,0,0,0,0,0};
        for (int c = 0; c < CDIM; ++c) {
            const double xv = (double)xb[(size_t)c << 12];   // wave-uniform
            #pragma unroll
            for (int j = 0; j < 8; ++j) {
                double t = xv - (double)er[c*KCODES + j];
                dd[j] = fma(t, t, dd[j]);
            }
        }
        double bd = 1e300; int bk = 0;
        #pragma unroll
        for (int j = 0; j < 8; ++j) {
            const int kk = lane*8 + j;
            if (dd[j] < bd) { bd = dd[j]; bk = kk; }
        }
        for (int off = 32; off; off >>= 1) {
            double od = __shfl_xor(bd, off);
            int    ok = __shfl_xor(bk, off);
            if (od < bd || (od == bd && ok < bk)) { bd = od; bk = ok; }
        }
        if (lane == 0) { ind_buf[n] = bk; out[OFF_IND + n] = (float)bk; }
        // patch quantize output: channel = lane (butterfly left final bk in every lane)
        out[((size_t)b << 18) + ((size_t)lane << 12) + hw] = emb[(lane << 9) + bk];
    }
}

// ---------------------------------------------------------------- stats via MFMA: sum[c][k] = X^T . OneHot(ind)
// 256 WGs x 1024 points; 32-pt chunks double-buffered in LDS.
// hi-only f16 (lo-pass dropped: sum error ~1e-2 worst-case << output thresholds).
__global__ __launch_bounds__(512) void k_stats(const float* __restrict__ in,
    const int* __restrict__ ind_buf, float* __restrict__ p_sum, float* __restrict__ p_cnt)
{
    __shared__ __align__(16) char xsm[2][CDIM*128];   // row c: [hi 32p | unused] halfs, byte ^= (c&7)<<4
    __shared__ int   ind_lds[2][32];
    __shared__ float s_cnt[KCODES];

    const int tid = threadIdx.x;
    const int wg  = blockIdx.x;
    const int n0  = wg << 10;                 // 1024 points, all same batch b
    const int b   = n0 >> 12;
    const float* inb = in + ((size_t)b << 18) + (n0 & 4095);

    for (int i = tid; i < KCODES; i += 512) s_cnt[i] = 0.f;

    // staging role: thread -> (channel, 4-point slot)
    const int sc  = tid >> 3;                 // 0..63
    const int sp  = (tid & 7) << 2;           // 0,4,..28
    const int sxr = (sc & 7) << 4;
    const int wb_hi = sc*128 + ((sp*2) ^ sxr);

    // compute role
    const int w  = tid >> 6, l = tid & 63;
    const int g  = l >> 4,  lc = l & 15;
    const int k0w = w << 6;                   // wave's 64-code band

    f32x4 acc[4][4];
    #pragma unroll
    for (int ci = 0; ci < 4; ++ci)
        #pragma unroll
        for (int kt = 0; kt < 4; ++kt) acc[ci][kt] = (f32x4){0.f, 0.f, 0.f, 0.f};

    // prologue: stage chunk 0
    {
        const float4 xv = *(const float4*)(inb + (size_t)sc*4096 + sp);
        half4v h;
        #pragma unroll
        for (int i = 0; i < 4; ++i) h[i] = (_Float16)(((const float*)&xv)[i]);
        *(half4v*)(&xsm[0][0] + wb_hi) = h;
        if (tid < 8) *(int4*)&ind_lds[0][tid*4] = *(const int4*)(ind_buf + n0 + tid*4);
    }

    for (int t = 0; t < 32; ++t) {
        __syncthreads();
        // issue next chunk's global loads early (T14)
        float4 nxt; int4 niv;
        if (t < 31) {
            nxt = *(const float4*)(inb + (size_t)sc*4096 + (t+1)*32 + sp);
            if (tid < 8) niv = *(const int4*)(ind_buf + n0 + (t+1)*32 + tid*4);
        }
        // counts for chunk t
        if (tid < 32) atomicAdd(&s_cnt[ind_lds[t & 1][tid]], 1.f);

        // A fragments (channels x points), hi only
        const char* xb = &xsm[t & 1][0];
        half8v ah[4];
        #pragma unroll
        for (int ci = 0; ci < 4; ++ci) {
            const int c  = (ci << 4) + lc;
            const int xr = (c & 7) << 4;
            ah[ci] = *(const half8v*)(xb + c*128 + ((g*16) ^ xr));
        }
        // OneHot B fragments from broadcast ind
        int idv[8];
        *(int4*)&idv[0] = *(const int4*)&ind_lds[t & 1][g*8];
        *(int4*)&idv[4] = *(const int4*)&ind_lds[t & 1][g*8 + 4];
        #pragma unroll
        for (int kt = 0; kt < 4; ++kt) {
            const int tgt = k0w + (kt << 4) + lc;
            half8v bf;
            #pragma unroll
            for (int j = 0; j < 8; ++j) bf[j] = (idv[j] == tgt) ? (_Float16)1.0f : (_Float16)0.0f;
            #pragma unroll
            for (int ci = 0; ci < 4; ++ci)
                acc[ci][kt] = __builtin_amdgcn_mfma_f32_16x16x32_f16(ah[ci], bf, acc[ci][kt], 0, 0, 0);
        }
        // write next chunk to the other buffer
        if (t < 31) {
            half4v h;
            #pragma unroll
            for (int i = 0; i < 4; ++i) h[i] = (_Float16)(((const float*)&nxt)[i]);
            *(half4v*)(&xsm[(t+1) & 1][0] + wb_hi) = h;
            if (tid < 8) *(int4*)&ind_lds[(t+1) & 1][tid*4] = niv;
        }
    }
    __syncthreads();

    // write partials: D row = channel (g*4+rr within tile), col = code (lc)
    float* ps = p_sum + (size_t)wg * (CDIM*KCODES);
    #pragma unroll
    for (int ci = 0; ci < 4; ++ci)
        #pragma unroll
        for (int kt = 0; kt < 4; ++kt)
            #pragma unroll
            for (int rr = 0; rr < 4; ++rr)
                ps[((ci << 4) + (g << 2) + rr)*KCODES + k0w + (kt << 4) + lc] = acc[ci][kt][rr];
    float* pc = p_cnt + wg * KCODES;
    for (int i = tid; i < KCODES; i += 512) pc[i] = s_cnt[i];
}

// ---------------------------------------------------------------- reduce stage 1: 256 -> 8 partials
__global__ __launch_bounds__(256) void k_reduce1(const float* __restrict__ p_sum,
    const float* __restrict__ p_cnt, float* __restrict__ partial8,
    float* __restrict__ cnt8, int wsl)
{
    const int ic = blockIdx.x & 31, ws = blockIdx.x >> 5;
    const int i4 = ic*1024 + threadIdx.x*4;
    const float* base = p_sum + (size_t)ws*wsl*(CDIM*KCODES) + i4;
    float4 s = make_float4(0.f, 0.f, 0.f, 0.f);
    for (int w = 0; w < wsl; ++w) {
        const float4 v = *(const float4*)(base + (size_t)w*(CDIM*KCODES));
        s.x += v.x; s.y += v.y; s.z += v.z; s.w += v.w;
    }
    *(float4*)(partial8 + ws*(CDIM*KCODES) + i4) = s;
    if (ic == 0) {
        for (int k = threadIdx.x; k < KCODES; k += 256) {
            float c = 0.f;
            for (int w = 0; w < wsl; ++w) c += p_cnt[(ws*wsl + w)*KCODES + k];
            cnt8[ws*KCODES + k] = c;
        }
    }
}

// ---------------------------------------------------------------- reduce stage 2: 8 -> 1
__global__ __launch_bounds__(256) void k_reduce2(const float* __restrict__ partial8,
    const float* __restrict__ cnt8, float* __restrict__ sum_tot, float* __restrict__ cnt_tot)
{
    const int i4 = (blockIdx.x*256 + threadIdx.x)*4;   // 32 blocks cover 32768
    float4 s = make_float4(0.f, 0.f, 0.f, 0.f);
    #pragma unroll
    for (int p = 0; p < 8; ++p) {
        const float4 v = *(const float4*)(partial8 + p*(CDIM*KCODES) + i4);
        s.x += v.x; s.y += v.y; s.z += v.z; s.w += v.w;
    }
    *(float4*)(sum_tot + i4) = s;
    if (blockIdx.x == 0) {
        for (int k = threadIdx.x; k < KCODES; k += 256) {
            float c = 0.f;
            #pragma unroll
            for (int p = 0; p < 8; ++p) c += cnt8[p*KCODES + k];
            cnt_tot[k] = c;
        }
    }
}

// ---------------------------------------------------------------- cluster_size, cs, diff
__global__ __launch_bounds__(512) void k_scalars(const float* __restrict__ csz,
    const float* __restrict__ cnt_tot, const float* __restrict__ diff_acc,
    float* __restrict__ out, float* __restrict__ cs_ws)
{
    __shared__ float red[512];
    const int k = threadIdx.x;
    const float ncs = csz[k]*0.99f + 0.01f*cnt_tot[k];
    out[OFF_CSZ + k] = ncs;
    red[k] = ncs;
    __syncthreads();
    for (int s = 256; s > 0; s >>= 1) { if (k < s) red[k] += red[k+s]; __syncthreads(); }
    const float n = red[0];
    cs_ws[k] = (ncs + 1e-5f) / (n + 0.00512f) * n;
    if (k == 0) out[OFF_DIFF] = diff_acc[0] * (1.f/16777216.f);
}

// ---------------------------------------------------------------- embedding_avg + embedding
__global__ void k_emb(const float* __restrict__ eavg, const float* __restrict__ sum_tot,
                      const float* __restrict__ cs_ws, float* __restrict__ out)
{
    const int i = blockIdx.x*blockDim.x + threadIdx.x;   // 32768
    const float avg = eavg[i]*0.99f + 0.01f*sum_tot[i];
    out[OFF_AVG + i] = avg;
    out[OFF_EMB + i] = avg / cs_ws[i & (KCODES-1)];
}

// ----------------------------------------------------------------
extern "C" void kernel_launch(void* const* d_in, const int* in_sizes, int n_in,
                              void* d_out, int out_size, void* d_ws, size_t ws_size,
                              hipStream_t stream)
{
    const float* in   = (const float*)d_in[0];
    const float* emb  = (const float*)d_in[1];
    const float* csz  = (const float*)d_in[2];
    const float* eavg = (const float*)d_in[3];
    float* out = (float*)d_out;
    char* ws = (char*)d_ws;

    // workspace layout (16B-aligned)
    int*      ind      = (int*)(ws + 2048);               //   1 MiB
    float*    diff_acc = (float*)(ws + 1050624);          //   4 B
    unsigned* nflag    = (unsigned*)(ws + 1050640);       //   4 B
    int*      flaglist = (int*)(ws + 1050656);            //   256 KiB
    float*    cs_ws    = (float*)(ws + 1312800);          //   2 KiB
    float*    cnt_tot  = (float*)(ws + 1314848);          //   2 KiB
    float*    sum_tot  = (float*)(ws + 1316896);          //   128 KiB
    const size_t off_part = 1447968;
    const int swgs = 256;
    float* p_sum    = (float*)(ws + off_part);
    float* p_cnt    = (float*)(ws + off_part + (size_t)swgs*(CDIM*KCODES)*4);
    float* partial8 = (float*)(ws + off_part + (size_t)swgs*133120);
    float* cnt8     = (float*)(ws + off_part + (size_t)swgs*133120 + 1048576);

    hipMemsetAsync(ws + 1050624, 0, 32, stream);          // diff_acc + nflag

    hipLaunchKernelGGL(k_main,    dim3(256),   dim3(512), 0, stream, in, emb, out, ind, diff_acc, nflag, flaglist);
    hipLaunchKernelGGL(k_refine,  dim3(256),   dim3(256), 0, stream, in, emb, nflag, flaglist, ind, out);
    hipLaunchKernelGGL(k_stats,   dim3(256),   dim3(512), 0, stream, in, ind, p_sum, p_cnt);
    hipLaunchKernelGGL(k_reduce1, dim3(256),   dim3(256), 0, stream, p_sum, p_cnt, partial8, cnt8, swgs >> 3);
    hipLaunchKernelGGL(k_reduce2, dim3(32),    dim3(256), 0, stream, partial8, cnt8, sum_tot, cnt_tot);
    hipLaunchKernelGGL(k_scalars, dim3(1),     dim3(512), 0, stream, csz, cnt_tot, diff_acc, out, cs_ws);
    hipLaunchKernelGGL(k_emb,     dim3(128),   dim3(256), 0, stream, eavg, sum_tot, cs_ws, out);
}

// Round 10
// 209.495 us; speedup vs baseline: 1.0571x; 1.0571x over previous
//
#include <hip/hip_runtime.h>
#include <cstdint>
#include <cstddef>

typedef _Float16 half4v __attribute__((ext_vector_type(4)));
typedef _Float16 half8v __attribute__((ext_vector_type(8)));
typedef float    f32x4  __attribute__((ext_vector_type(4)));

#define N_PTS   262144
#define CDIM    64
#define KCODES  512
#define TAUA    5e-3f          // acc-units; true-dist gap = 2*acc gap -> 1e-2
#define FLAG_CAP 65536u

// output offsets (floats): out, diff, embedding_ind, new_embedding, new_cluster_size, new_embedding_avg
#define OFF_DIFF 16777216u
#define OFF_IND  16777217u
#define OFF_EMB  17039361u
#define OFF_CSZ  17072129u
#define OFF_AVG  17072641u

// ---------------------------------------------------------------- main: MFMA f16x2-split distances + argmin
// acc = ee/2 + (-x)*e  ->  dist = 2*acc + xx  (argmin equivalent in acc units)
// Exact round-8 proven version (quantize fusion reverted: it cost +30us at 1 WG/CU vs ~15us standalone).
__global__ __launch_bounds__(512) void k_main(
    const float* __restrict__ in, const float* __restrict__ emb,
    float* __restrict__ out,
    int* __restrict__ ind_buf, float* __restrict__ diff_acc,
    unsigned* __restrict__ nflag, int* __restrict__ flaglist)
{
    // LDS: B_hi [64KiB] | B_lo [64KiB] | ee2 [2KiB]   (swizzled: byte ^= (col&7)<<4)
    __shared__ __align__(16) char bsm[133120];
    float* ee2_lds = (float*)(bsm + 131072);
    const int tid = threadIdx.x;

    // ---- stage codebook: fp32 -> f16 hi/lo, swizzled; ee2 computed inline ----
    {
        const int col = tid;                 // 512 threads = 512 cols
        const int xr  = (col & 7) << 4;
        float s = 0.f;
        #pragma unroll
        for (int c0 = 0; c0 < CDIM; c0 += 4) {
            float v[4];
            #pragma unroll
            for (int i = 0; i < 4; ++i) v[i] = emb[(c0 + i)*KCODES + col];
            half4v h, lo;
            #pragma unroll
            for (int i = 0; i < 4; ++i) {
                s = fmaf(v[i], v[i], s);
                _Float16 hh = (_Float16)v[i];
                h[i]  = hh;
                lo[i] = (_Float16)(v[i] - (float)hh);
            }
            const int wb = col*128 + ((c0*2) ^ xr);
            *(half4v*)(bsm + wb)         = h;
            *(half4v*)(bsm + 65536 + wb) = lo;
        }
        ee2_lds[col] = 0.5f * s;
    }
    __syncthreads();

    const int w  = tid >> 6, l = tid & 63;
    const int g  = l >> 4,  lc = l & 15;

    for (int r = 0; r < 2; ++r) {
        const int pbase = (blockIdx.x << 10) + (r << 9) + (w << 6);  // 64 points/wave
        const int b     = pbase >> 12;
        const float* inb = in + ((size_t)b << 18) + ((pbase & 4095) + lc);

        // ---- A fragments: negated x, exact f16 split; xx accumulated on the fly ----
        half8v ah[4][2], al[4][2];
        float xs = 0.f;
        #pragma unroll
        for (int t = 0; t < 4; ++t)
            #pragma unroll
            for (int s = 0; s < 2; ++s)
                #pragma unroll
                for (int j = 0; j < 8; ++j) {
                    const int c = s*32 + g*8 + j;
                    const float x = inb[(size_t)c*4096 + t*16];
                    xs = fmaf(x, x, xs);
                    const float xf = -x;
                    const _Float16 hh = (_Float16)xf;
                    ah[t][s][j] = hh;
                    al[t][s][j] = (_Float16)(xf - (float)hh);
                }

        float d1[4][4], d2[4][4]; int k1[4][4];
        #pragma unroll
        for (int t = 0; t < 4; ++t)
            #pragma unroll
            for (int rr = 0; rr < 4; ++rr) { d1[t][rr] = 3.4e38f; d2[t][rr] = 3.4e38f; k1[t][rr] = 0; }

        for (int ct = 0; ct < 32; ++ct) {
            const int col  = (ct << 4) + lc;
            const float sd = ee2_lds[col];
            const int rb   = col*128 + ((g*16) ^ ((col & 7) << 4));
            half8v bh0 = *(const half8v*)(bsm + rb);
            half8v bh1 = *(const half8v*)(bsm + (rb ^ 64));
            half8v bl0 = *(const half8v*)(bsm + 65536 + rb);
            half8v bl1 = *(const half8v*)(bsm + 65536 + (rb ^ 64));

            #pragma unroll
            for (int t = 0; t < 4; ++t) {
                // two independent 3-deep chains (K-halves s=0 / s=1)
                f32x4 acc0 = {sd, sd, sd, sd};
                f32x4 acc1 = {0.f, 0.f, 0.f, 0.f};
                acc0 = __builtin_amdgcn_mfma_f32_16x16x32_f16(al[t][0], bh0, acc0, 0, 0, 0);
                acc1 = __builtin_amdgcn_mfma_f32_16x16x32_f16(al[t][1], bh1, acc1, 0, 0, 0);
                acc0 = __builtin_amdgcn_mfma_f32_16x16x32_f16(ah[t][0], bl0, acc0, 0, 0, 0);
                acc1 = __builtin_amdgcn_mfma_f32_16x16x32_f16(ah[t][1], bl1, acc1, 0, 0, 0);
                acc0 = __builtin_amdgcn_mfma_f32_16x16x32_f16(ah[t][0], bh0, acc0, 0, 0, 0);
                acc1 = __builtin_amdgcn_mfma_f32_16x16x32_f16(ah[t][1], bh1, acc1, 0, 0, 0);
                #pragma unroll
                for (int rr = 0; rr < 4; ++rr) {
                    const float d = acc0[rr] + acc1[rr];
                    const bool cc = d < d1[t][rr];
                    d2[t][rr] = fminf(d2[t][rr], fmaxf(d, d1[t][rr]));
                    d1[t][rr] = fminf(d1[t][rr], d);
                    k1[t][rr] = cc ? col : k1[t][rr];
                }
            }
        }

        // ---- cross-lane best-2 merge over the 16 col-lanes ----
        #pragma unroll
        for (int m = 1; m <= 8; m <<= 1) {
            #pragma unroll
            for (int t = 0; t < 4; ++t)
                #pragma unroll
                for (int rr = 0; rr < 4; ++rr) {
                    const float od1 = __shfl_xor(d1[t][rr], m);
                    const int   ok1 = __shfl_xor(k1[t][rr], m);
                    const float od2 = __shfl_xor(d2[t][rr], m);
                    const float nd2 = fminf(fmaxf(d1[t][rr], od1), fminf(d2[t][rr], od2));
                    const bool take = (od1 < d1[t][rr]) || (od1 == d1[t][rr] && ok1 < k1[t][rr]);
                    d1[t][rr] = take ? od1 : d1[t][rr];
                    k1[t][rr] = take ? ok1 : k1[t][rr];
                    d2[t][rr] = nd2;
                }
        }

        // ---- outputs: indices, near-tie flags, diff partial ----
        float ds = 0.f;
        if (lc == 0) {
            #pragma unroll
            for (int t = 0; t < 4; ++t) {
                const int nb = pbase + t*16 + (g << 2);
                int4 iv = make_int4(k1[t][0], k1[t][1], k1[t][2], k1[t][3]);
                *(int4*)(ind_buf + nb) = iv;
                #pragma unroll
                for (int rr = 0; rr < 4; ++rr) {
                    out[OFF_IND + nb + rr] = (float)k1[t][rr];
                    ds += d1[t][rr];
                    if (d2[t][rr] - d1[t][rr] < TAUA) {
                        unsigned ix = atomicAdd(nflag, 1u);
                        if (ix < FLAG_CAP) flaglist[ix] = nb + rr;
                    }
                }
            }
        }
        #pragma unroll
        for (int m = 1; m < 64; m <<= 1) {
            ds += __shfl_xor(ds, m);
            xs += __shfl_xor(xs, m);
        }
        if (l == 0) atomicAdd(diff_acc, 2.f*ds + xs);
    }
}

// ---------------------------------------------------------------- f64 exact re-scan for near-ties
__global__ void k_refine(const float* __restrict__ in, const float* __restrict__ emb,
                         const unsigned* __restrict__ nflag, const int* __restrict__ flaglist,
                         int* __restrict__ ind_buf, float* __restrict__ out)
{
    const int gtid = blockIdx.x*blockDim.x + threadIdx.x;
    const int wid  = gtid >> 6;
    const int lane = threadIdx.x & 63;
    const int nw   = (gridDim.x * blockDim.x) >> 6;
    unsigned nf = *nflag; if (nf > FLAG_CAP) nf = FLAG_CAP;
    for (unsigned f = wid; f < nf; f += nw) {
        const int n = flaglist[f];
        const int b = n >> 12, hw = n & 4095;
        const float* xb = in + ((size_t)b << 18) + hw;
        const float* er = emb + lane*8;
        double dd[8] = {0,0,0,0,0,0,0,0};
        for (int c = 0; c < CDIM; ++c) {
            const double xv = (double)xb[(size_t)c << 12];   // wave-uniform
            #pragma unroll
            for (int j = 0; j < 8; ++j) {
                double t = xv - (double)er[c*KCODES + j];
                dd[j] = fma(t, t, dd[j]);
            }
        }
        double bd = 1e300; int bk = 0;
        #pragma unroll
        for (int j = 0; j < 8; ++j) {
            const int kk = lane*8 + j;
            if (dd[j] < bd) { bd = dd[j]; bk = kk; }
        }
        for (int off = 32; off; off >>= 1) {
            double od = __shfl_xor(bd, off);
            int    ok = __shfl_xor(bk, off);
            if (od < bd || (od == bd && ok < bk)) { bd = od; bk = ok; }
        }
        if (lane == 0) { ind_buf[n] = bk; out[OFF_IND + n] = (float)bk; }
    }
}

// ---------------------------------------------------------------- stats via MFMA: sum[c][k] = X^T . OneHot(ind)
// hi-only f16 (proven r9: sum error ~1e-2 << thresholds; dead-code columns exact)
__global__ __launch_bounds__(512) void k_stats(const float* __restrict__ in,
    const int* __restrict__ ind_buf, float* __restrict__ p_sum, float* __restrict__ p_cnt)
{
    __shared__ __align__(16) char xsm[2][CDIM*128];   // row c: [hi 32p | unused], byte ^= (c&7)<<4
    __shared__ int   ind_lds[2][32];
    __shared__ float s_cnt[KCODES];

    const int tid = threadIdx.x;
    const int wg  = blockIdx.x;
    const int n0  = wg << 10;                 // 1024 points, all same batch b
    const int b   = n0 >> 12;
    const float* inb = in + ((size_t)b << 18) + (n0 & 4095);

    for (int i = tid; i < KCODES; i += 512) s_cnt[i] = 0.f;

    const int sc  = tid >> 3;                 // staging: channel 0..63
    const int sp  = (tid & 7) << 2;           // 4-point slot
    const int sxr = (sc & 7) << 4;
    const int wb_hi = sc*128 + ((sp*2) ^ sxr);

    const int w  = tid >> 6, l = tid & 63;
    const int g  = l >> 4,  lc = l & 15;
    const int k0w = w << 6;                   // wave's 64-code band

    f32x4 acc[4][4];
    #pragma unroll
    for (int ci = 0; ci < 4; ++ci)
        #pragma unroll
        for (int kt = 0; kt < 4; ++kt) acc[ci][kt] = (f32x4){0.f, 0.f, 0.f, 0.f};

    // prologue: stage chunk 0
    {
        const float4 xv = *(const float4*)(inb + (size_t)sc*4096 + sp);
        half4v h;
        #pragma unroll
        for (int i = 0; i < 4; ++i) h[i] = (_Float16)(((const float*)&xv)[i]);
        *(half4v*)(&xsm[0][0] + wb_hi) = h;
        if (tid < 8) *(int4*)&ind_lds[0][tid*4] = *(const int4*)(ind_buf + n0 + tid*4);
    }

    for (int t = 0; t < 32; ++t) {
        __syncthreads();
        float4 nxt; int4 niv;
        if (t < 31) {
            nxt = *(const float4*)(inb + (size_t)sc*4096 + (t+1)*32 + sp);
            if (tid < 8) niv = *(const int4*)(ind_buf + n0 + (t+1)*32 + tid*4);
        }
        if (tid < 32) atomicAdd(&s_cnt[ind_lds[t & 1][tid]], 1.f);

        const char* xb = &xsm[t & 1][0];
        half8v ah[4];
        #pragma unroll
        for (int ci = 0; ci < 4; ++ci) {
            const int c  = (ci << 4) + lc;
            const int xr = (c & 7) << 4;
            ah[ci] = *(const half8v*)(xb + c*128 + ((g*16) ^ xr));
        }
        int idv[8];
        *(int4*)&idv[0] = *(const int4*)&ind_lds[t & 1][g*8];
        *(int4*)&idv[4] = *(const int4*)&ind_lds[t & 1][g*8 + 4];
        #pragma unroll
        for (int kt = 0; kt < 4; ++kt) {
            const int tgt = k0w + (kt << 4) + lc;
            half8v bf;
            #pragma unroll
            for (int j = 0; j < 8; ++j) bf[j] = (idv[j] == tgt) ? (_Float16)1.0f : (_Float16)0.0f;
            #pragma unroll
            for (int ci = 0; ci < 4; ++ci)
                acc[ci][kt] = __builtin_amdgcn_mfma_f32_16x16x32_f16(ah[ci], bf, acc[ci][kt], 0, 0, 0);
        }
        if (t < 31) {
            half4v h;
            #pragma unroll
            for (int i = 0; i < 4; ++i) h[i] = (_Float16)(((const float*)&nxt)[i]);
            *(half4v*)(&xsm[(t+1) & 1][0] + wb_hi) = h;
            if (tid < 8) *(int4*)&ind_lds[(t+1) & 1][tid*4] = niv;
        }
    }
    __syncthreads();

    float* ps = p_sum + (size_t)wg * (CDIM*KCODES);
    #pragma unroll
    for (int ci = 0; ci < 4; ++ci)
        #pragma unroll
        for (int kt = 0; kt < 4; ++kt)
            #pragma unroll
            for (int rr = 0; rr < 4; ++rr)
                ps[((ci << 4) + (g << 2) + rr)*KCODES + k0w + (kt << 4) + lc] = acc[ci][kt][rr];
    float* pc = p_cnt + wg * KCODES;
    for (int i = tid; i < KCODES; i += 512) pc[i] = s_cnt[i];
}

// ---------------------------------------------------------------- reduce stage 1: 256 -> 8 partials
__global__ __launch_bounds__(256) void k_reduce1(const float* __restrict__ p_sum,
    const float* __restrict__ p_cnt, float* __restrict__ partial8,
    float* __restrict__ cnt8, int wsl)
{
    const int ic = blockIdx.x & 31, ws = blockIdx.x >> 5;
    const int i4 = ic*1024 + threadIdx.x*4;
    const float* base = p_sum + (size_t)ws*wsl*(CDIM*KCODES) + i4;
    float4 s = make_float4(0.f, 0.f, 0.f, 0.f);
    for (int w = 0; w < wsl; ++w) {
        const float4 v = *(const float4*)(base + (size_t)w*(CDIM*KCODES));
        s.x += v.x; s.y += v.y; s.z += v.z; s.w += v.w;
    }
    *(float4*)(partial8 + ws*(CDIM*KCODES) + i4) = s;
    if (ic == 0) {
        for (int k = threadIdx.x; k < KCODES; k += 256) {
            float c = 0.f;
            for (int w = 0; w < wsl; ++w) c += p_cnt[(ws*wsl + w)*KCODES + k];
            cnt8[ws*KCODES + k] = c;
        }
    }
}

// ---------------------------------------------------------------- final: fused reduce2 + scalars + emb outputs
// 32 blocks x 512 thr. Every block redundantly reduces cnt8 (16KB) -> n, cs[512] in LDS;
// block 0 writes cluster_size + diff; each block reduces its slice of partial8 -> avg + embedding.
__global__ __launch_bounds__(512) void k_final(const float* __restrict__ partial8,
    const float* __restrict__ cnt8, const float* __restrict__ csz,
    const float* __restrict__ eavg, const float* __restrict__ diff_acc,
    float* __restrict__ out)
{
    __shared__ float red[512];
    __shared__ float cs_lds[512];
    const int k = threadIdx.x;
    float c = 0.f;
    #pragma unroll
    for (int p = 0; p < 8; ++p) c += cnt8[p*KCODES + k];
    const float ncs = csz[k]*0.99f + 0.01f*c;
    if (blockIdx.x == 0) out[OFF_CSZ + k] = ncs;
    red[k] = ncs;
    __syncthreads();
    for (int s = 256; s > 0; s >>= 1) { if (k < s) red[k] += red[k+s]; __syncthreads(); }
    const float n = red[0];
    cs_lds[k] = (ncs + 1e-5f) / (n + 0.00512f) * n;
    if (blockIdx.x == 0 && k == 0) out[OFF_DIFF] = diff_acc[0] * (1.f/16777216.f);
    __syncthreads();
    if (k < 256) {
        const int i = (blockIdx.x*256 + k)*4;        // 32*256*4 = 32768
        float4 s4 = make_float4(0.f, 0.f, 0.f, 0.f);
        #pragma unroll
        for (int p = 0; p < 8; ++p) {
            const float4 v = *(const float4*)(partial8 + p*(CDIM*KCODES) + i);
            s4.x += v.x; s4.y += v.y; s4.z += v.z; s4.w += v.w;
        }
        const float4 ea = *(const float4*)(eavg + i);
        const float a0 = ea.x*0.99f + 0.01f*s4.x;
        const float a1 = ea.y*0.99f + 0.01f*s4.y;
        const float a2 = ea.z*0.99f + 0.01f*s4.z;
        const float a3 = ea.w*0.99f + 0.01f*s4.w;
        const int kb = i & (KCODES-1);
        // scalar stores: OFF_AVG/OFF_EMB are odd offsets (float4 would be misaligned)
        out[OFF_AVG + i]     = a0;  out[OFF_AVG + i + 1] = a1;
        out[OFF_AVG + i + 2] = a2;  out[OFF_AVG + i + 3] = a3;
        out[OFF_EMB + i]     = a0 / cs_lds[kb];
        out[OFF_EMB + i + 1] = a1 / cs_lds[kb + 1];
        out[OFF_EMB + i + 2] = a2 / cs_lds[kb + 2];
        out[OFF_EMB + i + 3] = a3 / cs_lds[kb + 3];
    }
}

// ---------------------------------------------------------------- quantize output (NCHW, coalesced)
__global__ void k_quant(const float* __restrict__ emb, const int* __restrict__ ind_buf,
                        float* __restrict__ out)
{
    const int gid = blockIdx.x*blockDim.x + threadIdx.x;
    const int i  = gid << 2;
    const int hw = i & 4095;
    const int c  = (i >> 12) & 63;
    const int b  = i >> 18;
    const int n  = (b << 12) + hw;
    const int4 iv = *(const int4*)(ind_buf + n);
    const float* er = emb + (c << 9);
    float4 o = make_float4(er[iv.x], er[iv.y], er[iv.z], er[iv.w]);
    *(float4*)(out + i) = o;
}

// ----------------------------------------------------------------
extern "C" void kernel_launch(void* const* d_in, const int* in_sizes, int n_in,
                              void* d_out, int out_size, void* d_ws, size_t ws_size,
                              hipStream_t stream)
{
    const float* in   = (const float*)d_in[0];
    const float* emb  = (const float*)d_in[1];
    const float* csz  = (const float*)d_in[2];
    const float* eavg = (const float*)d_in[3];
    float* out = (float*)d_out;
    char* ws = (char*)d_ws;

    // workspace layout (16B-aligned)
    int*      ind      = (int*)(ws + 2048);               //   1 MiB
    float*    diff_acc = (float*)(ws + 1050624);          //   4 B
    unsigned* nflag    = (unsigned*)(ws + 1050640);       //   4 B
    int*      flaglist = (int*)(ws + 1050656);            //   256 KiB
    const size_t off_part = 1447968;
    const int swgs = 256;
    float* p_sum    = (float*)(ws + off_part);
    float* p_cnt    = (float*)(ws + off_part + (size_t)swgs*(CDIM*KCODES)*4);
    float* partial8 = (float*)(ws + off_part + (size_t)swgs*133120);
    float* cnt8     = (float*)(ws + off_part + (size_t)swgs*133120 + 1048576);

    hipMemsetAsync(ws + 1050624, 0, 32, stream);          // diff_acc + nflag

    hipLaunchKernelGGL(k_main,    dim3(256),   dim3(512), 0, stream, in, emb, out, ind, diff_acc, nflag, flaglist);
    hipLaunchKernelGGL(k_refine,  dim3(256),   dim3(256), 0, stream, in, emb, nflag, flaglist, ind, out);
    hipLaunchKernelGGL(k_quant,   dim3(16384), dim3(256), 0, stream, emb, ind, out);
    hipLaunchKernelGGL(k_stats,   dim3(256),   dim3(512), 0, stream, in, ind, p_sum, p_cnt);
    hipLaunchKernelGGL(k_reduce1, dim3(256),   dim3(256), 0, stream, p_sum, p_cnt, partial8, cnt8, swgs >> 3);
    hipLaunchKernelGGL(k_final,   dim3(32),    dim3(512), 0, stream, partial8, cnt8, csz, eavg, diff_acc, out);
}